// Round 4
// baseline (549.064 us; speedup 1.0000x reference)
//
#include <hip/hip_runtime.h>

#define NN 50000
#define NE 800000
#define DD 128
#define SCAN_NB 196   // ceil(NN/256)
#define GR 48         // rows per gemm block (multiple of 8; 50000 % 8 == 0 overall)

// workspace layout, element (4-byte) offsets
#define OF_DEG   0            // int[NN]
#define OF_DINV  50176        // float[NN]
#define OF_OFFS  100352       // int[NN+1]
#define OF_CURS  150784       // int[NN]
#define OF_BSUM  200960       // int[SCAN_NB]
#define OF_BPRE  201216       // int[SCAN_NB]
#define OF_CSRS  201472       // int[NE]
#define OF_CSRW  1001472      // float[NE]
#define OF_H     1801472      // float[NN*DD]  (16B-aligned)
#define OF_AGG   8201728      // float[NN*DD]

__global__ void k_init_deg(int* __restrict__ deg) {
    int i = blockIdx.x * blockDim.x + threadIdx.x;
    if (i < NN) deg[i] = 1;   // self-loop contributes 1
}

__global__ void k_count(const int* __restrict__ dst, int* __restrict__ deg) {
    int e = blockIdx.x * blockDim.x + threadIdx.x;
    if (e < NE) atomicAdd(&deg[dst[e]], 1);
}

// hierarchical scan over in-degrees (deg[i]-1), phase 1: per-block exclusive
__global__ void k_scan1(const int* __restrict__ deg, int* __restrict__ offs,
                        int* __restrict__ bsum) {
    __shared__ int sh[256];
    int tid = threadIdx.x;
    int i = blockIdx.x * 256 + tid;
    int v = (i < NN) ? (deg[i] - 1) : 0;
    sh[tid] = v;
    __syncthreads();
    for (int off = 1; off < 256; off <<= 1) {
        int t = (tid >= off) ? sh[tid - off] : 0;
        __syncthreads();
        sh[tid] += t;
        __syncthreads();
    }
    if (i < NN) offs[i] = sh[tid] - v;  // exclusive, block-local
    if (tid == 255) bsum[blockIdx.x] = sh[255];
}

// phase 2: single small block scans the 196 block sums
__global__ void k_scan2(const int* __restrict__ bsum, int* __restrict__ bpre,
                        int* __restrict__ offs) {
    __shared__ int sh[256];
    int tid = threadIdx.x;
    int v = (tid < SCAN_NB) ? bsum[tid] : 0;
    sh[tid] = v;
    __syncthreads();
    for (int off = 1; off < 256; off <<= 1) {
        int t = (tid >= off) ? sh[tid - off] : 0;
        __syncthreads();
        sh[tid] += t;
        __syncthreads();
    }
    if (tid < SCAN_NB) bpre[tid] = sh[tid] - v;
    if (tid == 255) offs[NN] = sh[255];  // total non-self-loop edges
}

// phase 3: add block prefix; also init curs and compute dinv (fused)
__global__ void k_scan3(int* __restrict__ offs, const int* __restrict__ bpre,
                        int* __restrict__ curs, const int* __restrict__ deg,
                        float* __restrict__ dinv) {
    int i = blockIdx.x * 256 + threadIdx.x;
    if (i < NN) {
        int o = offs[i] + bpre[blockIdx.x];
        offs[i] = o;
        curs[i] = o;
        dinv[i] = rsqrtf((float)deg[i]);
    }
}

__global__ void k_place(const int* __restrict__ src, const int* __restrict__ dst,
                        const float* __restrict__ dinv, int* __restrict__ curs,
                        int* __restrict__ csr_src, float* __restrict__ csr_w) {
    int e = blockIdx.x * blockDim.x + threadIdx.x;
    if (e < NE) {
        int s = src[e], d = dst[e];
        int p = atomicAdd(&curs[d], 1);
        csr_src[p] = s;
        csr_w[p] = dinv[s] * dinv[d];
    }
}

// Split-K GEMM: Y[r][j] = sum_k X[r][k] * W[k][j].
// 256 threads = 128 cols x 2 K-halves (kh is wave-uniform: waves 0-1 kh=0,
// waves 2-3 kh=1).  Thread holds 64 W values in VGPRs (registers actually
// stay resident, unlike the 128-element version -> VGPR_Count was 84 = spill).
// 8 rows per batch -> 8 independent FMA chains; halves combined via 4KB LDS.
__global__ __launch_bounds__(256, 3) void k_gemm(const float* __restrict__ X,
                                                 const float* __restrict__ W,
                                                 float* __restrict__ Y) {
    __shared__ float part[8][DD];   // 4 KB, col-consecutive -> 2-way bank alias (free)
    const int tid = threadIdx.x;
    const int col = tid & 127;
    const int kh  = tid >> 7;       // 0 or 1, wave-uniform
    float wreg[64];
#pragma unroll
    for (int kk = 0; kk < 64; ++kk)
        wreg[kk] = W[(kh * 64 + kk) * DD + col];
    int r0 = blockIdx.x * GR;
    int r1 = r0 + GR;
    if (r1 > NN) r1 = NN;
    // r1-r0 is always a multiple of 8 (50000 = 48*1041 + 32)
    for (int rb = r0; rb < r1; rb += 8) {
        float acc[8];
        const float4* xb = (const float4*)(X + (size_t)rb * DD + kh * 64);
#pragma unroll
        for (int rr = 0; rr < 8; ++rr) {
            const float4* xr = xb + rr * (DD / 4);  // wave-uniform address
            float a = 0.f;
#pragma unroll
            for (int k4 = 0; k4 < 16; ++k4) {
                float4 xv = xr[k4];
                a += xv.x * wreg[4 * k4] + xv.y * wreg[4 * k4 + 1] +
                     xv.z * wreg[4 * k4 + 2] + xv.w * wreg[4 * k4 + 3];
            }
            acc[rr] = a;
        }
        __syncthreads();   // protect part[] reuse from previous batch
        if (kh == 1) {
#pragma unroll
            for (int rr = 0; rr < 8; ++rr) part[rr][col] = acc[rr];
        }
        __syncthreads();
        if (kh == 0) {
#pragma unroll
            for (int rr = 0; rr < 8; ++rr)
                Y[(size_t)(rb + rr) * DD + col] = acc[rr] + part[rr][col];
        }
    }
}

// out[i] = relu( dinv[i]^2 * h[i] + sum_{e: dst==i} w_e * h[src_e] + bias )
// One wave per node.  Row split as 32 lanes x float4 (16B/lane); the two
// wave halves take interleaved edges and we unroll 2x -> 4 independent row
// gathers in flight per wave.  Halves combined with one shfl_xor(32).
__global__ void k_agg(const float* __restrict__ h, const float* __restrict__ dinv,
                      const int* __restrict__ offs, const int* __restrict__ csr_src,
                      const float* __restrict__ csr_w, const float* __restrict__ bias,
                      float* __restrict__ out) {
    int gid = blockIdx.x * blockDim.x + threadIdx.x;
    int node = gid >> 6;
    if (node >= NN) return;
    int lane = threadIdx.x & 63;
    int half = lane >> 5;
    int c = lane & 31;
    const float4* hb = (const float4*)h;  // row r at hb[r*32 + c]
    float4 a0 = {0.f, 0.f, 0.f, 0.f};
    float4 a1 = {0.f, 0.f, 0.f, 0.f};
    int e  = offs[node] + half;
    int e1 = offs[node + 1];
    for (; e + 2 < e1; e += 4) {
        int   s0 = csr_src[e];     float w0 = csr_w[e];
        int   s1 = csr_src[e + 2]; float w1 = csr_w[e + 2];
        float4 v0 = hb[(size_t)s0 * 32 + c];
        float4 v1 = hb[(size_t)s1 * 32 + c];
        a0.x += w0 * v0.x; a0.y += w0 * v0.y; a0.z += w0 * v0.z; a0.w += w0 * v0.w;
        a1.x += w1 * v1.x; a1.y += w1 * v1.y; a1.z += w1 * v1.z; a1.w += w1 * v1.w;
    }
    if (e < e1) {
        int s0 = csr_src[e]; float w0 = csr_w[e];
        float4 v0 = hb[(size_t)s0 * 32 + c];
        a0.x += w0 * v0.x; a0.y += w0 * v0.y; a0.z += w0 * v0.z; a0.w += w0 * v0.w;
    }
    if (half == 0) {  // self-loop term, counted once
        float di = dinv[node];
        float sw = di * di;
        float4 v = hb[(size_t)node * 32 + c];
        a0.x += sw * v.x; a0.y += sw * v.y; a0.z += sw * v.z; a0.w += sw * v.w;
    }
    a0.x += a1.x; a0.y += a1.y; a0.z += a1.z; a0.w += a1.w;
    a0.x += __shfl_xor(a0.x, 32, 64);
    a0.y += __shfl_xor(a0.y, 32, 64);
    a0.z += __shfl_xor(a0.z, 32, 64);
    a0.w += __shfl_xor(a0.w, 32, 64);
    if (half == 0) {
        float4 bv = ((const float4*)bias)[c];
        float4 o;
        o.x = fmaxf(a0.x + bv.x, 0.f);
        o.y = fmaxf(a0.y + bv.y, 0.f);
        o.z = fmaxf(a0.z + bv.z, 0.f);
        o.w = fmaxf(a0.w + bv.w, 0.f);
        ((float4*)(out + (size_t)node * DD))[c] = o;
    }
}

extern "C" void kernel_launch(void* const* d_in, const int* in_sizes, int n_in,
                              void* d_out, int out_size, void* d_ws, size_t ws_size,
                              hipStream_t stream) {
    const float* x  = (const float*)d_in[0];
    const int*   ei = (const int*)d_in[1];
    const float* W1 = (const float*)d_in[2];
    const float* b1 = (const float*)d_in[3];
    const float* W2 = (const float*)d_in[4];
    const float* b2 = (const float*)d_in[5];
    float* out = (float*)d_out;

    const int* src = ei;        // edge_index[0]
    const int* dst = ei + NE;   // edge_index[1]

    int*   wsi  = (int*)d_ws;
    float* wsf  = (float*)d_ws;
    int*   deg  = wsi + OF_DEG;
    float* dinv = wsf + OF_DINV;
    int*   offs = wsi + OF_OFFS;
    int*   curs = wsi + OF_CURS;
    int*   bsum = wsi + OF_BSUM;
    int*   bpre = wsi + OF_BPRE;
    int*   csrs = wsi + OF_CSRS;
    float* csrw = wsf + OF_CSRW;
    float* hbuf = wsf + OF_H;
    float* abuf = wsf + OF_AGG;

    const int gemm_blocks = (NN + GR - 1) / GR;  // 1042

    hipLaunchKernelGGL(k_init_deg, dim3((NN + 255) / 256), dim3(256), 0, stream, deg);
    hipLaunchKernelGGL(k_count,    dim3((NE + 255) / 256), dim3(256), 0, stream, dst, deg);
    hipLaunchKernelGGL(k_scan1,    dim3(SCAN_NB), dim3(256), 0, stream, deg, offs, bsum);
    hipLaunchKernelGGL(k_scan2,    dim3(1), dim3(256), 0, stream, bsum, bpre, offs);
    hipLaunchKernelGGL(k_scan3,    dim3(SCAN_NB), dim3(256), 0, stream, offs, bpre, curs, deg, dinv);
    hipLaunchKernelGGL(k_place,    dim3((NE + 255) / 256), dim3(256), 0, stream,
                       src, dst, dinv, curs, csrs, csrw);

    // layer 1: h = x @ W1 ; agg -> +b1, relu
    hipLaunchKernelGGL(k_gemm, dim3(gemm_blocks), dim3(256), 0, stream, x, W1, hbuf);
    hipLaunchKernelGGL(k_agg,  dim3((NN * 64 + 255) / 256), dim3(256), 0, stream,
                       hbuf, dinv, offs, csrs, csrw, b1, abuf);
    // layer 2
    hipLaunchKernelGGL(k_gemm, dim3(gemm_blocks), dim3(256), 0, stream, abuf, W2, hbuf);
    hipLaunchKernelGGL(k_agg,  dim3((NN * 64 + 255) / 256), dim3(256), 0, stream,
                       hbuf, dinv, offs, csrs, csrw, b2, out);
}

// Round 5
// 330.534 us; speedup vs baseline: 1.6611x; 1.6611x over previous
//
#include <hip/hip_runtime.h>

#define NN 50000
#define NE 800000
#define DD 128
#define SCAN_NB 196   // ceil(NN/256)
#define NSTRIP 3125   // NN/16

// workspace layout, element (4-byte word) offsets
#define OF_DEG   0            // int[NN]
#define OF_DINV  50176        // float[NN]
#define OF_OFFS  100352       // int[NN+1]
#define OF_CURS  150784       // int[NN]
#define OF_BSUM  200960       // int[SCAN_NB]
#define OF_BPRE  201216       // int[SCAN_NB]
#define OF_CSRS  201472       // int[NE]
#define OF_CSRW  1001472      // float[NE]
#define OF_H     1801472      // float[NN*DD] fp32 GEMM output
#define OF_XH    8201728      // ushort[NN*DD] bf16-hi  (reused: x for L1, agg1-out for L2)
#define OF_XL    11401728     // ushort[NN*DD] bf16-lo
#define OF_W1H   14601728     // ushort[16384] W1 hi, fragment order
#define OF_W1L   14609920
#define OF_W2H   14618112
#define OF_W2L   14626304     // end 14634496 words = 58.5 MB

typedef __attribute__((ext_vector_type(8))) short bf8_t;   // 8 bf16 = 4 VGPRs
typedef __attribute__((ext_vector_type(4))) float f32x4;

static __device__ __forceinline__ unsigned short f2bf(float f) {
    unsigned int u = __float_as_uint(f);
    unsigned int r = (u + 0x7fffu + ((u >> 16) & 1u)) >> 16;   // RNE
    return (unsigned short)r;
}
static __device__ __forceinline__ float bf2f(unsigned short h) {
    return __uint_as_float(((unsigned int)h) << 16);
}

__global__ void k_init_deg(int* __restrict__ deg) {
    int i = blockIdx.x * blockDim.x + threadIdx.x;
    if (i < NN) deg[i] = 1;   // self-loop contributes 1
}

__global__ void k_count(const int* __restrict__ dst, int* __restrict__ deg) {
    int e = blockIdx.x * blockDim.x + threadIdx.x;
    if (e < NE) atomicAdd(&deg[dst[e]], 1);
}

// hierarchical scan over in-degrees (deg[i]-1), phase 1: per-block exclusive
__global__ void k_scan1(const int* __restrict__ deg, int* __restrict__ offs,
                        int* __restrict__ bsum) {
    __shared__ int sh[256];
    int tid = threadIdx.x;
    int i = blockIdx.x * 256 + tid;
    int v = (i < NN) ? (deg[i] - 1) : 0;
    sh[tid] = v;
    __syncthreads();
    for (int off = 1; off < 256; off <<= 1) {
        int t = (tid >= off) ? sh[tid - off] : 0;
        __syncthreads();
        sh[tid] += t;
        __syncthreads();
    }
    if (i < NN) offs[i] = sh[tid] - v;  // exclusive, block-local
    if (tid == 255) bsum[blockIdx.x] = sh[255];
}

__global__ void k_scan2(const int* __restrict__ bsum, int* __restrict__ bpre,
                        int* __restrict__ offs) {
    __shared__ int sh[256];
    int tid = threadIdx.x;
    int v = (tid < SCAN_NB) ? bsum[tid] : 0;
    sh[tid] = v;
    __syncthreads();
    for (int off = 1; off < 256; off <<= 1) {
        int t = (tid >= off) ? sh[tid - off] : 0;
        __syncthreads();
        sh[tid] += t;
        __syncthreads();
    }
    if (tid < SCAN_NB) bpre[tid] = sh[tid] - v;
    if (tid == 255) offs[NN] = sh[255];
}

__global__ void k_scan3(int* __restrict__ offs, const int* __restrict__ bpre,
                        int* __restrict__ curs, const int* __restrict__ deg,
                        float* __restrict__ dinv) {
    int i = blockIdx.x * 256 + threadIdx.x;
    if (i < NN) {
        int o = offs[i] + bpre[blockIdx.x];
        offs[i] = o;
        curs[i] = o;
        dinv[i] = rsqrtf((float)deg[i]);
    }
}

__global__ void k_place(const int* __restrict__ src, const int* __restrict__ dst,
                        const float* __restrict__ dinv, int* __restrict__ curs,
                        int* __restrict__ csr_src, float* __restrict__ csr_w) {
    int e = blockIdx.x * blockDim.x + threadIdx.x;
    if (e < NE) {
        int s = src[e], d = dst[e];
        int p = atomicAdd(&curs[d], 1);
        csr_src[p] = s;
        csr_w[p] = dinv[s] * dinv[d];
    }
}

// fp32 -> bf16 hi/lo split, elementwise (row-major layout IS the A-frag layout)
__global__ void k_xconv(const float* __restrict__ x, ushort* __restrict__ xh,
                        ushort* __restrict__ xl) {
    size_t i = ((size_t)blockIdx.x * blockDim.x + threadIdx.x) * 4;
    if (i >= (size_t)NN * DD) return;
    float4 v = *(const float4*)(x + i);
    ushort4 h, l;
    h.x = f2bf(v.x); l.x = f2bf(v.x - bf2f(h.x));
    h.y = f2bf(v.y); l.y = f2bf(v.y - bf2f(h.y));
    h.z = f2bf(v.z); l.z = f2bf(v.z - bf2f(h.z));
    h.w = f2bf(v.w); l.w = f2bf(v.w - bf2f(h.w));
    *(ushort4*)(xh + i) = h;
    *(ushort4*)(xl + i) = l;
}

// W[k][n] fp32 -> bf16 hi/lo in B-fragment-contiguous order:
// frag g=(ntile*4+kk)*64+lane holds B[k=kk*32+(lane>>4)*8+j][n=ntile*16+(lane&15)]
__global__ void k_wconv(const float* __restrict__ W, ushort* __restrict__ wh,
                        ushort* __restrict__ wl) {
    int g = blockIdx.x * blockDim.x + threadIdx.x;
    if (g >= 2048) return;
    int ntile = g >> 8;
    int kk = (g >> 6) & 3;
    int lane = g & 63;
    int k0 = kk * 32 + ((lane >> 4) * 8);
    int col = ntile * 16 + (lane & 15);
#pragma unroll
    for (int j = 0; j < 8; ++j) {
        float w = W[(k0 + j) * DD + col];
        unsigned short h = f2bf(w);
        wh[(size_t)g * 8 + j] = h;
        wl[(size_t)g * 8 + j] = f2bf(w - bf2f(h));
    }
}

// MFMA GEMM, split-bf16 (3 products: hi*hi + hi*lo + lo*hi ~ fp32 accuracy).
// One wave per 16-row strip; 8 N-tiles of 16 cols; K=128 as 4 steps of 32.
// A frags: 16B direct global loads from row-major bf16 x.
// B frags: 16B loads from the 32KB fragment-ordered W tables (L2-resident).
__global__ __launch_bounds__(256) void k_mgemm(const ushort* __restrict__ xh,
                                               const ushort* __restrict__ xl,
                                               const ushort* __restrict__ wh,
                                               const ushort* __restrict__ wl,
                                               float* __restrict__ Y) {
    int wave = threadIdx.x >> 6;
    int lane = threadIdx.x & 63;
    int strip = blockIdx.x * 4 + wave;
    if (strip >= NSTRIP) return;
    int rb = strip << 4;
    int m = lane & 15;
    int quad = lane >> 4;
    const ushort* arh = xh + (size_t)(rb + m) * DD;
    const ushort* arl = xl + (size_t)(rb + m) * DD;
    f32x4 acc[8];
#pragma unroll
    for (int t = 0; t < 8; ++t) acc[t] = (f32x4){0.f, 0.f, 0.f, 0.f};
#pragma unroll
    for (int kk = 0; kk < 4; ++kk) {
        bf8_t ah = *(const bf8_t*)(arh + kk * 32 + quad * 8);
        bf8_t al = *(const bf8_t*)(arl + kk * 32 + quad * 8);
#pragma unroll
        for (int t = 0; t < 8; ++t) {
            size_t bo = ((size_t)(t * 4 + kk) * 64 + lane) * 8;
            bf8_t bh = *(const bf8_t*)(wh + bo);
            bf8_t bl = *(const bf8_t*)(wl + bo);
            acc[t] = __builtin_amdgcn_mfma_f32_16x16x32_bf16(ah, bh, acc[t], 0, 0, 0);
            acc[t] = __builtin_amdgcn_mfma_f32_16x16x32_bf16(ah, bl, acc[t], 0, 0, 0);
            acc[t] = __builtin_amdgcn_mfma_f32_16x16x32_bf16(al, bh, acc[t], 0, 0, 0);
        }
    }
    // C/D layout (m89-verified): col = lane&15, row = quad*4 + reg
#pragma unroll
    for (int t = 0; t < 8; ++t) {
        float* yb = Y + (size_t)(rb + quad * 4) * DD + t * 16 + m;
#pragma unroll
        for (int r = 0; r < 4; ++r) yb[(size_t)r * DD] = acc[t][r];
    }
}

// out[i] = relu( dinv[i]^2 * h[i] + sum_{e: dst==i} w_e * h[src_e] + bias )
// One wave per node; 32 lanes x float4; halves take interleaved edges, 2x
// unroll -> 4 independent gathers in flight.  BF16OUT: write hi/lo split
// (feeds next MFMA GEMM) instead of fp32.
template <bool BF16OUT>
__global__ void k_agg(const float* __restrict__ h, const float* __restrict__ dinv,
                      const int* __restrict__ offs, const int* __restrict__ csr_src,
                      const float* __restrict__ csr_w, const float* __restrict__ bias,
                      float* __restrict__ outf, ushort* __restrict__ oh,
                      ushort* __restrict__ ol) {
    int gid = blockIdx.x * blockDim.x + threadIdx.x;
    int node = gid >> 6;
    if (node >= NN) return;
    int lane = threadIdx.x & 63;
    int half = lane >> 5;
    int c = lane & 31;
    const float4* hb = (const float4*)h;  // row r at hb[r*32 + c]
    float4 a0 = {0.f, 0.f, 0.f, 0.f};
    float4 a1 = {0.f, 0.f, 0.f, 0.f};
    int e  = offs[node] + half;
    int e1 = offs[node + 1];
    for (; e + 2 < e1; e += 4) {
        int   s0 = csr_src[e];     float w0 = csr_w[e];
        int   s1 = csr_src[e + 2]; float w1 = csr_w[e + 2];
        float4 v0 = hb[(size_t)s0 * 32 + c];
        float4 v1 = hb[(size_t)s1 * 32 + c];
        a0.x += w0 * v0.x; a0.y += w0 * v0.y; a0.z += w0 * v0.z; a0.w += w0 * v0.w;
        a1.x += w1 * v1.x; a1.y += w1 * v1.y; a1.z += w1 * v1.z; a1.w += w1 * v1.w;
    }
    if (e < e1) {
        int s0 = csr_src[e]; float w0 = csr_w[e];
        float4 v0 = hb[(size_t)s0 * 32 + c];
        a0.x += w0 * v0.x; a0.y += w0 * v0.y; a0.z += w0 * v0.z; a0.w += w0 * v0.w;
    }
    if (half == 0) {  // self-loop term, counted once
        float di = dinv[node];
        float sw = di * di;
        float4 v = hb[(size_t)node * 32 + c];
        a0.x += sw * v.x; a0.y += sw * v.y; a0.z += sw * v.z; a0.w += sw * v.w;
    }
    a0.x += a1.x; a0.y += a1.y; a0.z += a1.z; a0.w += a1.w;
    a0.x += __shfl_xor(a0.x, 32, 64);
    a0.y += __shfl_xor(a0.y, 32, 64);
    a0.z += __shfl_xor(a0.z, 32, 64);
    a0.w += __shfl_xor(a0.w, 32, 64);
    if (half == 0) {
        float4 bv = ((const float4*)bias)[c];
        float4 o;
        o.x = fmaxf(a0.x + bv.x, 0.f);
        o.y = fmaxf(a0.y + bv.y, 0.f);
        o.z = fmaxf(a0.z + bv.z, 0.f);
        o.w = fmaxf(a0.w + bv.w, 0.f);
        if (BF16OUT) {
            ushort4 hh, ll;
            hh.x = f2bf(o.x); ll.x = f2bf(o.x - bf2f(hh.x));
            hh.y = f2bf(o.y); ll.y = f2bf(o.y - bf2f(hh.y));
            hh.z = f2bf(o.z); ll.z = f2bf(o.z - bf2f(hh.z));
            hh.w = f2bf(o.w); ll.w = f2bf(o.w - bf2f(hh.w));
            *(ushort4*)(oh + (size_t)node * DD + 4 * c) = hh;
            *(ushort4*)(ol + (size_t)node * DD + 4 * c) = ll;
        } else {
            ((float4*)(outf + (size_t)node * DD))[c] = o;
        }
    }
}

extern "C" void kernel_launch(void* const* d_in, const int* in_sizes, int n_in,
                              void* d_out, int out_size, void* d_ws, size_t ws_size,
                              hipStream_t stream) {
    const float* x  = (const float*)d_in[0];
    const int*   ei = (const int*)d_in[1];
    const float* W1 = (const float*)d_in[2];
    const float* b1 = (const float*)d_in[3];
    const float* W2 = (const float*)d_in[4];
    const float* b2 = (const float*)d_in[5];
    float* out = (float*)d_out;

    const int* src = ei;        // edge_index[0]
    const int* dst = ei + NE;   // edge_index[1]

    int*    wsi  = (int*)d_ws;
    float*  wsf  = (float*)d_ws;
    ushort* wsu  = (ushort*)d_ws;
    int*    deg  = wsi + OF_DEG;
    float*  dinv = wsf + OF_DINV;
    int*    offs = wsi + OF_OFFS;
    int*    curs = wsi + OF_CURS;
    int*    bsum = wsi + OF_BSUM;
    int*    bpre = wsi + OF_BPRE;
    int*    csrs = wsi + OF_CSRS;
    float*  csrw = wsf + OF_CSRW;
    float*  hbuf = wsf + OF_H;
    ushort* xh   = wsu + (size_t)OF_XH * 2;
    ushort* xl   = wsu + (size_t)OF_XL * 2;
    ushort* w1h  = wsu + (size_t)OF_W1H * 2;
    ushort* w1l  = wsu + (size_t)OF_W1L * 2;
    ushort* w2h  = wsu + (size_t)OF_W2H * 2;
    ushort* w2l  = wsu + (size_t)OF_W2L * 2;

    hipLaunchKernelGGL(k_init_deg, dim3((NN + 255) / 256), dim3(256), 0, stream, deg);
    hipLaunchKernelGGL(k_count,    dim3((NE + 255) / 256), dim3(256), 0, stream, dst, deg);
    hipLaunchKernelGGL(k_scan1,    dim3(SCAN_NB), dim3(256), 0, stream, deg, offs, bsum);
    hipLaunchKernelGGL(k_scan2,    dim3(1), dim3(256), 0, stream, bsum, bpre, offs);
    hipLaunchKernelGGL(k_scan3,    dim3(SCAN_NB), dim3(256), 0, stream, offs, bpre, curs, deg, dinv);
    hipLaunchKernelGGL(k_place,    dim3((NE + 255) / 256), dim3(256), 0, stream,
                       src, dst, dinv, curs, csrs, csrw);

    // one-time conversions
    hipLaunchKernelGGL(k_xconv, dim3((NN * DD / 4 + 255) / 256), dim3(256), 0, stream, x, xh, xl);
    hipLaunchKernelGGL(k_wconv, dim3(8), dim3(256), 0, stream, W1, w1h, w1l);
    hipLaunchKernelGGL(k_wconv, dim3(8), dim3(256), 0, stream, W2, w2h, w2l);

    const int gblocks = (NSTRIP + 3) / 4;  // 782

    // layer 1: h = x @ W1 (MFMA) ; agg -> +b1, relu -> bf16 pair (reuses xh/xl)
    hipLaunchKernelGGL(k_mgemm, dim3(gblocks), dim3(256), 0, stream, xh, xl, w1h, w1l, hbuf);
    hipLaunchKernelGGL(k_agg<true>, dim3((NN * 64 + 255) / 256), dim3(256), 0, stream,
                       hbuf, dinv, offs, csrs, csrw, b1, (float*)nullptr, xh, xl);
    // layer 2
    hipLaunchKernelGGL(k_mgemm, dim3(gblocks), dim3(256), 0, stream, xh, xl, w2h, w2l, hbuf);
    hipLaunchKernelGGL(k_agg<false>, dim3((NN * 64 + 255) / 256), dim3(256), 0, stream,
                       hbuf, dinv, offs, csrs, csrw, b2, out, (ushort*)nullptr, (ushort*)nullptr);
}

// Round 6
// 297.536 us; speedup vs baseline: 1.8454x; 1.1109x over previous
//
#include <hip/hip_runtime.h>

#define NN 50000
#define NE 800000
#define DD 128
#define SCAN_NB 196   // ceil(NN/256)
#define NSTRIP 3125   // NN/16

// workspace layout, element (4-byte word) offsets
#define OF_DEG   0            // int[NN]
#define OF_DINV  50176        // float[NN]
#define OF_OFFS  100352       // int[NN+1]
#define OF_CURS  150784       // int[NN]
#define OF_BSUM  200960       // int[SCAN_NB]
#define OF_BPRE  201216       // int[SCAN_NB]
#define OF_CSR   201472       // int2[NE] packed (src, bitcast w) -> 1.6M words
#define OF_HB    1801472      // ushort[NN*DD] bf16 GEMM output (agg gather table)
#define OF_XH    5001472      // ushort[NN*DD] bf16-hi (x for L1, agg1-out for L2)
#define OF_XL    8201472      // ushort[NN*DD] bf16-lo
#define OF_W1H   11401472     // ushort[16384] fragment order
#define OF_W1L   11409664
#define OF_W2H   11417856
#define OF_W2L   11426048     // end 11434240 words = 45.7 MB

typedef __attribute__((ext_vector_type(8))) short bf8_t;   // 8 bf16 = 4 VGPRs
typedef __attribute__((ext_vector_type(4))) float f32x4;

static __device__ __forceinline__ unsigned short f2bf(float f) {
    unsigned int u = __float_as_uint(f);
    unsigned int r = (u + 0x7fffu + ((u >> 16) & 1u)) >> 16;   // RNE
    return (unsigned short)r;
}
static __device__ __forceinline__ float bf2f(unsigned short h) {
    return __uint_as_float(((unsigned int)h) << 16);
}

__global__ void k_init_deg(int* __restrict__ deg) {
    int i = blockIdx.x * blockDim.x + threadIdx.x;
    if (i < NN) deg[i] = 1;   // self-loop contributes 1
}

__global__ void k_count(const int* __restrict__ dst, int* __restrict__ deg) {
    int e = blockIdx.x * blockDim.x + threadIdx.x;
    if (e < NE) atomicAdd(&deg[dst[e]], 1);
}

// hierarchical scan over in-degrees (deg[i]-1), phase 1: per-block exclusive
__global__ void k_scan1(const int* __restrict__ deg, int* __restrict__ offs,
                        int* __restrict__ bsum) {
    __shared__ int sh[256];
    int tid = threadIdx.x;
    int i = blockIdx.x * 256 + tid;
    int v = (i < NN) ? (deg[i] - 1) : 0;
    sh[tid] = v;
    __syncthreads();
    for (int off = 1; off < 256; off <<= 1) {
        int t = (tid >= off) ? sh[tid - off] : 0;
        __syncthreads();
        sh[tid] += t;
        __syncthreads();
    }
    if (i < NN) offs[i] = sh[tid] - v;  // exclusive, block-local
    if (tid == 255) bsum[blockIdx.x] = sh[255];
}

__global__ void k_scan2(const int* __restrict__ bsum, int* __restrict__ bpre,
                        int* __restrict__ offs) {
    __shared__ int sh[256];
    int tid = threadIdx.x;
    int v = (tid < SCAN_NB) ? bsum[tid] : 0;
    sh[tid] = v;
    __syncthreads();
    for (int off = 1; off < 256; off <<= 1) {
        int t = (tid >= off) ? sh[tid - off] : 0;
        __syncthreads();
        sh[tid] += t;
        __syncthreads();
    }
    if (tid < SCAN_NB) bpre[tid] = sh[tid] - v;
    if (tid == 255) offs[NN] = sh[255];
}

__global__ void k_scan3(int* __restrict__ offs, const int* __restrict__ bpre,
                        int* __restrict__ curs, const int* __restrict__ deg,
                        float* __restrict__ dinv) {
    int i = blockIdx.x * 256 + threadIdx.x;
    if (i < NN) {
        int o = offs[i] + bpre[blockIdx.x];
        offs[i] = o;
        curs[i] = o;
        dinv[i] = rsqrtf((float)deg[i]);
    }
}

// one packed 8B scatter per edge (halves dirtied lines vs two 4B arrays)
__global__ void k_place(const int* __restrict__ src, const int* __restrict__ dst,
                        const float* __restrict__ dinv, int* __restrict__ curs,
                        int2* __restrict__ csr) {
    int e = blockIdx.x * blockDim.x + threadIdx.x;
    if (e < NE) {
        int s = src[e], d = dst[e];
        float w = dinv[s] * dinv[d];
        int p = atomicAdd(&curs[d], 1);
        int2 pk;
        pk.x = s;
        pk.y = __float_as_int(w);
        csr[p] = pk;
    }
}

// fp32 -> bf16 hi/lo split, elementwise (row-major layout IS the A-frag layout)
__global__ void k_xconv(const float* __restrict__ x, ushort* __restrict__ xh,
                        ushort* __restrict__ xl) {
    size_t i = ((size_t)blockIdx.x * blockDim.x + threadIdx.x) * 4;
    if (i >= (size_t)NN * DD) return;
    float4 v = *(const float4*)(x + i);
    ushort4 h, l;
    h.x = f2bf(v.x); l.x = f2bf(v.x - bf2f(h.x));
    h.y = f2bf(v.y); l.y = f2bf(v.y - bf2f(h.y));
    h.z = f2bf(v.z); l.z = f2bf(v.z - bf2f(h.z));
    h.w = f2bf(v.w); l.w = f2bf(v.w - bf2f(h.w));
    *(ushort4*)(xh + i) = h;
    *(ushort4*)(xl + i) = l;
}

// W[k][n] fp32 -> bf16 hi/lo in B-fragment-contiguous order:
// frag g=(ntile*4+kk)*64+lane holds B[k=kk*32+(lane>>4)*8+j][n=ntile*16+(lane&15)]
__global__ void k_wconv(const float* __restrict__ W, ushort* __restrict__ wh,
                        ushort* __restrict__ wl) {
    int g = blockIdx.x * blockDim.x + threadIdx.x;
    if (g >= 2048) return;
    int ntile = g >> 8;
    int kk = (g >> 6) & 3;
    int lane = g & 63;
    int k0 = kk * 32 + ((lane >> 4) * 8);
    int col = ntile * 16 + (lane & 15);
#pragma unroll
    for (int j = 0; j < 8; ++j) {
        float w = W[(k0 + j) * DD + col];
        unsigned short h = f2bf(w);
        wh[(size_t)g * 8 + j] = h;
        wl[(size_t)g * 8 + j] = f2bf(w - bf2f(h));
    }
}

// MFMA GEMM, split-bf16 (hi*hi + hi*lo + lo*hi ~ fp32 accuracy).
// One wave per 16-row strip; 8 N-tiles of 16 cols; K=128 as 4 steps of 32.
// Output written as bf16 (sole consumer is the bf16 gather in k_agg).
__global__ __launch_bounds__(256) void k_mgemm(const ushort* __restrict__ xh,
                                               const ushort* __restrict__ xl,
                                               const ushort* __restrict__ wh,
                                               const ushort* __restrict__ wl,
                                               ushort* __restrict__ Yb) {
    int wave = threadIdx.x >> 6;
    int lane = threadIdx.x & 63;
    int strip = blockIdx.x * 4 + wave;
    if (strip >= NSTRIP) return;
    int rb = strip << 4;
    int m = lane & 15;
    int quad = lane >> 4;
    const ushort* arh = xh + (size_t)(rb + m) * DD;
    const ushort* arl = xl + (size_t)(rb + m) * DD;
    f32x4 acc[8];
#pragma unroll
    for (int t = 0; t < 8; ++t) acc[t] = (f32x4){0.f, 0.f, 0.f, 0.f};
#pragma unroll
    for (int kk = 0; kk < 4; ++kk) {
        bf8_t ah = *(const bf8_t*)(arh + kk * 32 + quad * 8);
        bf8_t al = *(const bf8_t*)(arl + kk * 32 + quad * 8);
#pragma unroll
        for (int t = 0; t < 8; ++t) {
            size_t bo = ((size_t)(t * 4 + kk) * 64 + lane) * 8;
            bf8_t bh = *(const bf8_t*)(wh + bo);
            bf8_t bl = *(const bf8_t*)(wl + bo);
            acc[t] = __builtin_amdgcn_mfma_f32_16x16x32_bf16(ah, bh, acc[t], 0, 0, 0);
            acc[t] = __builtin_amdgcn_mfma_f32_16x16x32_bf16(ah, bl, acc[t], 0, 0, 0);
            acc[t] = __builtin_amdgcn_mfma_f32_16x16x32_bf16(al, bh, acc[t], 0, 0, 0);
        }
    }
    // C/D layout (m89-verified): col = lane&15, row = quad*4 + reg
#pragma unroll
    for (int t = 0; t < 8; ++t) {
#pragma unroll
        for (int r = 0; r < 4; ++r)
            Yb[(size_t)(rb + quad * 4 + r) * DD + t * 16 + m] = f2bf(acc[t][r]);
    }
}

// out[i] = relu( dinv[i]^2 * h[i] + sum_{e: dst==i} w_e * h[src_e] + bias )
// h is bf16 (256B rows).  One wave per node; 32 lanes x ushort4 (8B/lane);
// halves take interleaved edges, 2x unroll -> 4 independent gathers in
// flight.  BF16OUT: write hi/lo split (feeds next MFMA GEMM).
template <bool BF16OUT>
__global__ void k_agg(const ushort* __restrict__ h, const float* __restrict__ dinv,
                      const int* __restrict__ offs, const int2* __restrict__ csr,
                      const float* __restrict__ bias,
                      float* __restrict__ outf, ushort* __restrict__ oh,
                      ushort* __restrict__ ol) {
    int gid = blockIdx.x * blockDim.x + threadIdx.x;
    int node = gid >> 6;
    if (node >= NN) return;
    int lane = threadIdx.x & 63;
    int half = lane >> 5;
    int c = lane & 31;
    float4 a0 = {0.f, 0.f, 0.f, 0.f};
    float4 a1 = {0.f, 0.f, 0.f, 0.f};
    int e  = offs[node] + half;
    int e1 = offs[node + 1];
    for (; e + 2 < e1; e += 4) {
        int2 p0 = csr[e];
        int2 p1 = csr[e + 2];
        float w0 = __int_as_float(p0.y);
        float w1 = __int_as_float(p1.y);
        ushort4 v0 = *(const ushort4*)(h + (size_t)p0.x * DD + 4 * c);
        ushort4 v1 = *(const ushort4*)(h + (size_t)p1.x * DD + 4 * c);
        a0.x += w0 * bf2f(v0.x); a0.y += w0 * bf2f(v0.y);
        a0.z += w0 * bf2f(v0.z); a0.w += w0 * bf2f(v0.w);
        a1.x += w1 * bf2f(v1.x); a1.y += w1 * bf2f(v1.y);
        a1.z += w1 * bf2f(v1.z); a1.w += w1 * bf2f(v1.w);
    }
    if (e < e1) {
        int2 p0 = csr[e];
        float w0 = __int_as_float(p0.y);
        ushort4 v0 = *(const ushort4*)(h + (size_t)p0.x * DD + 4 * c);
        a0.x += w0 * bf2f(v0.x); a0.y += w0 * bf2f(v0.y);
        a0.z += w0 * bf2f(v0.z); a0.w += w0 * bf2f(v0.w);
    }
    if (half == 0) {  // self-loop term, counted once
        float di = dinv[node];
        float sw = di * di;
        ushort4 v = *(const ushort4*)(h + (size_t)node * DD + 4 * c);
        a0.x += sw * bf2f(v.x); a0.y += sw * bf2f(v.y);
        a0.z += sw * bf2f(v.z); a0.w += sw * bf2f(v.w);
    }
    a0.x += a1.x; a0.y += a1.y; a0.z += a1.z; a0.w += a1.w;
    a0.x += __shfl_xor(a0.x, 32, 64);
    a0.y += __shfl_xor(a0.y, 32, 64);
    a0.z += __shfl_xor(a0.z, 32, 64);
    a0.w += __shfl_xor(a0.w, 32, 64);
    if (half == 0) {
        float4 bv = ((const float4*)bias)[c];
        float4 o;
        o.x = fmaxf(a0.x + bv.x, 0.f);
        o.y = fmaxf(a0.y + bv.y, 0.f);
        o.z = fmaxf(a0.z + bv.z, 0.f);
        o.w = fmaxf(a0.w + bv.w, 0.f);
        if (BF16OUT) {
            ushort4 hh, ll;
            hh.x = f2bf(o.x); ll.x = f2bf(o.x - bf2f(hh.x));
            hh.y = f2bf(o.y); ll.y = f2bf(o.y - bf2f(hh.y));
            hh.z = f2bf(o.z); ll.z = f2bf(o.z - bf2f(hh.z));
            hh.w = f2bf(o.w); ll.w = f2bf(o.w - bf2f(hh.w));
            *(ushort4*)(oh + (size_t)node * DD + 4 * c) = hh;
            *(ushort4*)(ol + (size_t)node * DD + 4 * c) = ll;
        } else {
            ((float4*)(outf + (size_t)node * DD))[c] = o;
        }
    }
}

extern "C" void kernel_launch(void* const* d_in, const int* in_sizes, int n_in,
                              void* d_out, int out_size, void* d_ws, size_t ws_size,
                              hipStream_t stream) {
    const float* x  = (const float*)d_in[0];
    const int*   ei = (const int*)d_in[1];
    const float* W1 = (const float*)d_in[2];
    const float* b1 = (const float*)d_in[3];
    const float* W2 = (const float*)d_in[4];
    const float* b2 = (const float*)d_in[5];
    float* out = (float*)d_out;

    const int* src = ei;        // edge_index[0]
    const int* dst = ei + NE;   // edge_index[1]

    int*    wsi  = (int*)d_ws;
    float*  wsf  = (float*)d_ws;
    ushort* wsu  = (ushort*)d_ws;
    int*    deg  = wsi + OF_DEG;
    float*  dinv = wsf + OF_DINV;
    int*    offs = wsi + OF_OFFS;
    int*    curs = wsi + OF_CURS;
    int*    bsum = wsi + OF_BSUM;
    int*    bpre = wsi + OF_BPRE;
    int2*   csr  = (int2*)(wsi + OF_CSR);
    ushort* hb   = wsu + (size_t)OF_HB * 2;
    ushort* xh   = wsu + (size_t)OF_XH * 2;
    ushort* xl   = wsu + (size_t)OF_XL * 2;
    ushort* w1h  = wsu + (size_t)OF_W1H * 2;
    ushort* w1l  = wsu + (size_t)OF_W1L * 2;
    ushort* w2h  = wsu + (size_t)OF_W2H * 2;
    ushort* w2l  = wsu + (size_t)OF_W2L * 2;

    hipLaunchKernelGGL(k_init_deg, dim3((NN + 255) / 256), dim3(256), 0, stream, deg);
    hipLaunchKernelGGL(k_count,    dim3((NE + 255) / 256), dim3(256), 0, stream, dst, deg);
    hipLaunchKernelGGL(k_scan1,    dim3(SCAN_NB), dim3(256), 0, stream, deg, offs, bsum);
    hipLaunchKernelGGL(k_scan2,    dim3(1), dim3(256), 0, stream, bsum, bpre, offs);
    hipLaunchKernelGGL(k_scan3,    dim3(SCAN_NB), dim3(256), 0, stream, offs, bpre, curs, deg, dinv);
    hipLaunchKernelGGL(k_place,    dim3((NE + 255) / 256), dim3(256), 0, stream,
                       src, dst, dinv, curs, csr);

    // one-time conversions
    hipLaunchKernelGGL(k_xconv, dim3((NN * DD / 4 + 255) / 256), dim3(256), 0, stream, x, xh, xl);
    hipLaunchKernelGGL(k_wconv, dim3(8), dim3(256), 0, stream, W1, w1h, w1l);
    hipLaunchKernelGGL(k_wconv, dim3(8), dim3(256), 0, stream, W2, w2h, w2l);

    const int gblocks = (NSTRIP + 3) / 4;  // 782

    // layer 1: h = x @ W1 (MFMA, bf16 out) ; agg -> +b1, relu -> bf16 hi/lo
    hipLaunchKernelGGL(k_mgemm, dim3(gblocks), dim3(256), 0, stream, xh, xl, w1h, w1l, hb);
    hipLaunchKernelGGL(k_agg<true>, dim3((NN * 64 + 255) / 256), dim3(256), 0, stream,
                       hb, dinv, offs, csr, b1, (float*)nullptr, xh, xl);
    // layer 2
    hipLaunchKernelGGL(k_mgemm, dim3(gblocks), dim3(256), 0, stream, xh, xl, w2h, w2l, hb);
    hipLaunchKernelGGL(k_agg<false>, dim3((NN * 64 + 255) / 256), dim3(256), 0, stream,
                       hb, dinv, offs, csr, b2, out, (ushort*)nullptr, (ushort*)nullptr);
}

// Round 7
// 279.008 us; speedup vs baseline: 1.9679x; 1.0664x over previous
//
#include <hip/hip_runtime.h>

#define NN 50000
#define NE 800000
#define DD 128
#define SCAN_NB 196   // ceil(NN/256)
#define NSTRIP 3125   // NN/16

// workspace layout, element (4-byte word) offsets
#define OF_DEG   0            // int[NN]
#define OF_DINV  50176        // float[NN]
#define OF_OFFS  100352       // int[NN+1]
#define OF_CURS  150784       // int[NN]
#define OF_BSUM  200960       // int[SCAN_NB]
#define OF_BPRE  201216       // int[SCAN_NB]
#define OF_CSRU  201472       // ushort[NE] src-only CSR (1.6 MB -> fits per-XCD L2)
#define OF_G     601472       // ushort[NN*DD] bf16 g = dinv*h gather table
#define OF_X2    3801472      // float[NN*DD] layer-2 input
#define OF_W1H   10201472     // ushort[16384] fragment order
#define OF_W1L   10209664
#define OF_W2H   10217856
#define OF_W2L   10226048     // end 10234240 words = 40.9 MB

typedef __attribute__((ext_vector_type(8))) short bf8_t;   // 8 bf16 = 4 VGPRs
typedef __attribute__((ext_vector_type(4))) float f32x4;

static __device__ __forceinline__ unsigned short f2bf(float f) {
    unsigned int u = __float_as_uint(f);
    unsigned int r = (u + 0x7fffu + ((u >> 16) & 1u)) >> 16;   // RNE
    return (unsigned short)r;
}
static __device__ __forceinline__ float bf2f(unsigned short h) {
    return __uint_as_float(((unsigned int)h) << 16);
}

__global__ void k_init_deg(int* __restrict__ deg) {
    int i = blockIdx.x * blockDim.x + threadIdx.x;
    if (i < NN) deg[i] = 1;   // self-loop contributes 1
}

__global__ void k_count(const int* __restrict__ dst, int* __restrict__ deg) {
    int e = blockIdx.x * blockDim.x + threadIdx.x;
    if (e < NE) atomicAdd(&deg[dst[e]], 1);
}

// hierarchical scan over in-degrees (deg[i]-1), phase 1: per-block exclusive
__global__ void k_scan1(const int* __restrict__ deg, int* __restrict__ offs,
                        int* __restrict__ bsum) {
    __shared__ int sh[256];
    int tid = threadIdx.x;
    int i = blockIdx.x * 256 + tid;
    int v = (i < NN) ? (deg[i] - 1) : 0;
    sh[tid] = v;
    __syncthreads();
    for (int off = 1; off < 256; off <<= 1) {
        int t = (tid >= off) ? sh[tid - off] : 0;
        __syncthreads();
        sh[tid] += t;
        __syncthreads();
    }
    if (i < NN) offs[i] = sh[tid] - v;  // exclusive, block-local
    if (tid == 255) bsum[blockIdx.x] = sh[255];
}

__global__ void k_scan2(const int* __restrict__ bsum, int* __restrict__ bpre,
                        int* __restrict__ offs) {
    __shared__ int sh[256];
    int tid = threadIdx.x;
    int v = (tid < SCAN_NB) ? bsum[tid] : 0;
    sh[tid] = v;
    __syncthreads();
    for (int off = 1; off < 256; off <<= 1) {
        int t = (tid >= off) ? sh[tid - off] : 0;
        __syncthreads();
        sh[tid] += t;
        __syncthreads();
    }
    if (tid < SCAN_NB) bpre[tid] = sh[tid] - v;
    if (tid == 255) offs[NN] = sh[255];
}

__global__ void k_scan3(int* __restrict__ offs, const int* __restrict__ bpre,
                        int* __restrict__ curs, const int* __restrict__ deg,
                        float* __restrict__ dinv) {
    int i = blockIdx.x * 256 + threadIdx.x;
    if (i < NN) {
        int o = offs[i] + bpre[blockIdx.x];
        offs[i] = o;
        curs[i] = o;
        dinv[i] = rsqrtf((float)deg[i]);
    }
}

// one 2B scatter per edge into a 1.6MB array (fits per-XCD L2 -> merges)
__global__ void k_place(const int* __restrict__ src, const int* __restrict__ dst,
                        int* __restrict__ curs, ushort* __restrict__ csru) {
    int e = blockIdx.x * blockDim.x + threadIdx.x;
    if (e < NE) {
        int s = src[e], d = dst[e];
        int p = atomicAdd(&curs[d], 1);
        csru[p] = (ushort)s;
    }
}

// W[k][n] fp32 -> bf16 hi/lo in B-fragment-contiguous order:
// frag g=(ntile*4+kk)*64+lane holds B[k=kk*32+(lane>>4)*8+j][n=ntile*16+(lane&15)]
__global__ void k_wconv(const float* __restrict__ W, ushort* __restrict__ wh,
                        ushort* __restrict__ wl) {
    int g = blockIdx.x * blockDim.x + threadIdx.x;
    if (g >= 2048) return;
    int ntile = g >> 8;
    int kk = (g >> 6) & 3;
    int lane = g & 63;
    int k0 = kk * 32 + ((lane >> 4) * 8);
    int col = ntile * 16 + (lane & 15);
#pragma unroll
    for (int j = 0; j < 8; ++j) {
        float w = W[(k0 + j) * DD + col];
        unsigned short h = f2bf(w);
        wh[(size_t)g * 8 + j] = h;
        wl[(size_t)g * 8 + j] = f2bf(w - bf2f(h));
    }
}

// MFMA GEMM, split-bf16 (hi*hi + hi*lo + lo*hi ~ fp32 accuracy).
// Reads fp32 X directly, Dekker-splits in-register (kills the xconv pass).
// Epilogue scales rows by dinv and stores bf16 g = dinv * (X@W).
__global__ __launch_bounds__(256) void k_mgemm(const float* __restrict__ X,
                                               const ushort* __restrict__ wh,
                                               const ushort* __restrict__ wl,
                                               const float* __restrict__ dinv,
                                               ushort* __restrict__ G) {
    int wave = threadIdx.x >> 6;
    int lane = threadIdx.x & 63;
    int strip = blockIdx.x * 4 + wave;
    if (strip >= NSTRIP) return;
    int rb = strip << 4;
    int m = lane & 15;
    int quad = lane >> 4;
    const float* ar = X + (size_t)(rb + m) * DD;
    f32x4 acc[8];
#pragma unroll
    for (int t = 0; t < 8; ++t) acc[t] = (f32x4){0.f, 0.f, 0.f, 0.f};
#pragma unroll
    for (int kk = 0; kk < 4; ++kk) {
        float4 xa = *(const float4*)(ar + kk * 32 + quad * 8);
        float4 xb = *(const float4*)(ar + kk * 32 + quad * 8 + 4);
        float xs[8] = {xa.x, xa.y, xa.z, xa.w, xb.x, xb.y, xb.z, xb.w};
        bf8_t ah, al;
#pragma unroll
        for (int j = 0; j < 8; ++j) {
            unsigned short hh = f2bf(xs[j]);
            ah[j] = (short)hh;
            al[j] = (short)f2bf(xs[j] - bf2f(hh));
        }
#pragma unroll
        for (int t = 0; t < 8; ++t) {
            size_t bo = ((size_t)(t * 4 + kk) * 64 + lane) * 8;
            bf8_t bh = *(const bf8_t*)(wh + bo);
            bf8_t bl = *(const bf8_t*)(wl + bo);
            acc[t] = __builtin_amdgcn_mfma_f32_16x16x32_bf16(ah, bh, acc[t], 0, 0, 0);
            acc[t] = __builtin_amdgcn_mfma_f32_16x16x32_bf16(ah, bl, acc[t], 0, 0, 0);
            acc[t] = __builtin_amdgcn_mfma_f32_16x16x32_bf16(al, bh, acc[t], 0, 0, 0);
        }
    }
    // C/D layout (m89-verified): col = lane&15, row = quad*4 + reg
    float dv[4];
#pragma unroll
    for (int r = 0; r < 4; ++r) dv[r] = dinv[rb + quad * 4 + r];
#pragma unroll
    for (int t = 0; t < 8; ++t) {
#pragma unroll
        for (int r = 0; r < 4; ++r)
            G[(size_t)(rb + quad * 4 + r) * DD + t * 16 + m] = f2bf(dv[r] * acc[t][r]);
    }
}

// out[i] = relu( dinv[i] * ( sum_{e: dst==i} g[src_e] + g[i] ) + bias )
// g is bf16 (256B rows), pre-scaled by dinv[src].  One wave per node;
// 32 lanes x ushort4 (8B/lane); halves take interleaved edges, 2x unroll
// -> 4 independent gathers in flight.  No per-edge weight at all.
__global__ void k_agg(const ushort* __restrict__ g, const float* __restrict__ dinv,
                      const int* __restrict__ offs, const ushort* __restrict__ csru,
                      const float* __restrict__ bias, float* __restrict__ outf) {
    int gid = blockIdx.x * blockDim.x + threadIdx.x;
    int node = gid >> 6;
    if (node >= NN) return;
    int lane = threadIdx.x & 63;
    int half = lane >> 5;
    int c = lane & 31;
    float4 a0 = {0.f, 0.f, 0.f, 0.f};
    float4 a1 = {0.f, 0.f, 0.f, 0.f};
    int e  = offs[node] + half;
    int e1 = offs[node + 1];
    for (; e + 2 < e1; e += 4) {
        int s0 = csru[e];
        int s1 = csru[e + 2];
        ushort4 v0 = *(const ushort4*)(g + (size_t)s0 * DD + 4 * c);
        ushort4 v1 = *(const ushort4*)(g + (size_t)s1 * DD + 4 * c);
        a0.x += bf2f(v0.x); a0.y += bf2f(v0.y); a0.z += bf2f(v0.z); a0.w += bf2f(v0.w);
        a1.x += bf2f(v1.x); a1.y += bf2f(v1.y); a1.z += bf2f(v1.z); a1.w += bf2f(v1.w);
    }
    if (e < e1) {
        int s0 = csru[e];
        ushort4 v0 = *(const ushort4*)(g + (size_t)s0 * DD + 4 * c);
        a0.x += bf2f(v0.x); a0.y += bf2f(v0.y); a0.z += bf2f(v0.z); a0.w += bf2f(v0.w);
    }
    if (half == 0) {  // self-loop term: dinv^2*h = dinv*g, counted once
        ushort4 v = *(const ushort4*)(g + (size_t)node * DD + 4 * c);
        a0.x += bf2f(v.x); a0.y += bf2f(v.y); a0.z += bf2f(v.z); a0.w += bf2f(v.w);
    }
    a0.x += a1.x; a0.y += a1.y; a0.z += a1.z; a0.w += a1.w;
    a0.x += __shfl_xor(a0.x, 32, 64);
    a0.y += __shfl_xor(a0.y, 32, 64);
    a0.z += __shfl_xor(a0.z, 32, 64);
    a0.w += __shfl_xor(a0.w, 32, 64);
    if (half == 0) {
        float di = dinv[node];
        float4 bv = ((const float4*)bias)[c];
        float4 o;
        o.x = fmaxf(di * a0.x + bv.x, 0.f);
        o.y = fmaxf(di * a0.y + bv.y, 0.f);
        o.z = fmaxf(di * a0.z + bv.z, 0.f);
        o.w = fmaxf(di * a0.w + bv.w, 0.f);
        ((float4*)(outf + (size_t)node * DD))[c] = o;
    }
}

extern "C" void kernel_launch(void* const* d_in, const int* in_sizes, int n_in,
                              void* d_out, int out_size, void* d_ws, size_t ws_size,
                              hipStream_t stream) {
    const float* x  = (const float*)d_in[0];
    const int*   ei = (const int*)d_in[1];
    const float* W1 = (const float*)d_in[2];
    const float* b1 = (const float*)d_in[3];
    const float* W2 = (const float*)d_in[4];
    const float* b2 = (const float*)d_in[5];
    float* out = (float*)d_out;

    const int* src = ei;        // edge_index[0]
    const int* dst = ei + NE;   // edge_index[1]

    int*    wsi  = (int*)d_ws;
    float*  wsf  = (float*)d_ws;
    ushort* wsu  = (ushort*)d_ws;
    int*    deg  = wsi + OF_DEG;
    float*  dinv = wsf + OF_DINV;
    int*    offs = wsi + OF_OFFS;
    int*    curs = wsi + OF_CURS;
    int*    bsum = wsi + OF_BSUM;
    int*    bpre = wsi + OF_BPRE;
    ushort* csru = wsu + (size_t)OF_CSRU * 2;
    ushort* gbuf = wsu + (size_t)OF_G * 2;
    float*  x2   = wsf + OF_X2;
    ushort* w1h  = wsu + (size_t)OF_W1H * 2;
    ushort* w1l  = wsu + (size_t)OF_W1L * 2;
    ushort* w2h  = wsu + (size_t)OF_W2H * 2;
    ushort* w2l  = wsu + (size_t)OF_W2L * 2;

    hipLaunchKernelGGL(k_init_deg, dim3((NN + 255) / 256), dim3(256), 0, stream, deg);
    hipLaunchKernelGGL(k_count,    dim3((NE + 255) / 256), dim3(256), 0, stream, dst, deg);
    hipLaunchKernelGGL(k_scan1,    dim3(SCAN_NB), dim3(256), 0, stream, deg, offs, bsum);
    hipLaunchKernelGGL(k_scan2,    dim3(1), dim3(256), 0, stream, bsum, bpre, offs);
    hipLaunchKernelGGL(k_scan3,    dim3(SCAN_NB), dim3(256), 0, stream, offs, bpre, curs, deg, dinv);
    hipLaunchKernelGGL(k_place,    dim3((NE + 255) / 256), dim3(256), 0, stream,
                       src, dst, curs, csru);

    hipLaunchKernelGGL(k_wconv, dim3(8), dim3(256), 0, stream, W1, w1h, w1l);
    hipLaunchKernelGGL(k_wconv, dim3(8), dim3(256), 0, stream, W2, w2h, w2l);

    const int gblocks = (NSTRIP + 3) / 4;  // 782

    // layer 1: g = dinv*(x @ W1) (MFMA, bf16) ; agg -> relu(dinv*sum + b1) fp32
    hipLaunchKernelGGL(k_mgemm, dim3(gblocks), dim3(256), 0, stream, x, w1h, w1l, dinv, gbuf);
    hipLaunchKernelGGL(k_agg,   dim3((NN * 64 + 255) / 256), dim3(256), 0, stream,
                       gbuf, dinv, offs, csru, b1, x2);
    // layer 2
    hipLaunchKernelGGL(k_mgemm, dim3(gblocks), dim3(256), 0, stream, x2, w2h, w2l, dinv, gbuf);
    hipLaunchKernelGGL(k_agg,   dim3((NN * 64 + 255) / 256), dim3(256), 0, stream,
                       gbuf, dinv, offs, csru, b2, out);
}

// Round 8
// 232.156 us; speedup vs baseline: 2.3651x; 1.2018x over previous
//
#include <hip/hip_runtime.h>

#define NN 50000
#define NE 800000
#define DD 128
#define NSTRIP 3125   // NN/16
#define NB 196        // dst>>8 buckets (49999>>8 == 195)
#define CHUNK 4096    // edges per shuf/hist block; grid = ceil(NE/CHUNK) = 196
#define MAXB 6144     // bucket capacity (mean 4082, sigma ~64 -> +32 sigma)

// workspace layout, element (4-byte word) offsets
#define OF_BCNT  0            // int[256] bucket counts
#define OF_BBASE 256          // int[257] bucket bases
#define OF_BCUR  768          // int[256] bucket cursors
#define OF_DINV  1024         // float[NN]
#define OF_OFFS  51200        // int[NN+1]
#define OF_TMP   101632       // uint[NE] packed (src<<8 | dstlow)  (3.2 MB)
#define OF_CSRU  901632       // ushort[NE] sorted src  (1.6 MB)
#define OF_G     1301632      // ushort[NN*DD] bf16 g = dinv*h gather table
#define OF_X2    4501632      // float[NN*DD] layer-2 input
#define OF_W1H   10901632     // ushort[16384] fragment order
#define OF_W1L   10909824
#define OF_W2H   10918016
#define OF_W2L   10926208     // end 10934400 words = 43.7 MB

typedef __attribute__((ext_vector_type(8))) short bf8_t;   // 8 bf16 = 4 VGPRs
typedef __attribute__((ext_vector_type(4))) float f32x4;

static __device__ __forceinline__ unsigned short f2bf(float f) {
    unsigned int u = __float_as_uint(f);
    unsigned int r = (u + 0x7fffu + ((u >> 16) & 1u)) >> 16;   // RNE
    return (unsigned short)r;
}
static __device__ __forceinline__ float bf2f(unsigned short h) {
    return __uint_as_float(((unsigned int)h) << 16);
}

__global__ void k_zero(int* __restrict__ bcnt) {
    bcnt[threadIdx.x] = 0;
}

// 256-bucket histogram of dst>>8, LDS-aggregated
__global__ void k_hist(const int* __restrict__ dst, int* __restrict__ bcnt) {
    __shared__ int lc[256];
    int tid = threadIdx.x;
    lc[tid] = 0;
    __syncthreads();
    int e0 = blockIdx.x * CHUNK;
    int e1 = e0 + CHUNK; if (e1 > NE) e1 = NE;
    for (int e = e0 + tid; e < e1; e += 256)
        atomicAdd(&lc[dst[e] >> 8], 1);
    __syncthreads();
    if (lc[tid]) atomicAdd(&bcnt[tid], lc[tid]);
}

// single-block scan of bucket counts -> bases + cursors; offs[NN] = NE
__global__ void k_bscan(const int* __restrict__ bcnt, int* __restrict__ bbase,
                        int* __restrict__ bcur, int* __restrict__ offs) {
    __shared__ int sh[256];
    int tid = threadIdx.x;
    int v = bcnt[tid];
    sh[tid] = v;
    __syncthreads();
    for (int o = 1; o < 256; o <<= 1) {
        int t = (tid >= o) ? sh[tid - o] : 0;
        __syncthreads();
        sh[tid] += t;
        __syncthreads();
    }
    bbase[tid] = sh[tid] - v;
    bcur[tid]  = sh[tid] - v;
    if (tid == 255) bbase[256] = sh[255];
    if (tid == 0) offs[NN] = NE;
}

// shuffle edges into coarse buckets.  Per block: LDS histogram of its chunk,
// ONE global atomic per touched bucket to reserve a contiguous run, then
// write packed entries -> per-block addresses form ~contiguous runs per
// bucket (lines mostly written by a single block -> no cross-XCD bouncing).
__global__ void k_shuf(const int* __restrict__ src, const int* __restrict__ dst,
                       int* __restrict__ bcur, unsigned int* __restrict__ tmp) {
    __shared__ int lcnt[256];
    __shared__ int lbase[256];
    __shared__ int lcur[256];
    int tid = threadIdx.x;
    lcnt[tid] = 0;
    __syncthreads();
    int e0 = blockIdx.x * CHUNK;
    int e1 = e0 + CHUNK; if (e1 > NE) e1 = NE;
    for (int e = e0 + tid; e < e1; e += 256)
        atomicAdd(&lcnt[dst[e] >> 8], 1);
    __syncthreads();
    if (lcnt[tid]) lbase[tid] = atomicAdd(&bcur[tid], lcnt[tid]);
    lcur[tid] = 0;
    __syncthreads();
    for (int e = e0 + tid; e < e1; e += 256) {
        int d = dst[e], s = src[e];
        int b = d >> 8;
        int r = atomicAdd(&lcur[b], 1);
        tmp[lbase[b] + r] = ((unsigned int)s << 8) | (unsigned int)(d & 255);
    }
}

// per-bucket LDS counting sort -> final CSR slab, offs[], dinv[].
// One block per bucket; the 2B output region is block-exclusive (~8KB),
// so scattered stores merge in a single XCD's L2.
__global__ __launch_bounds__(256) void k_sort(const int* __restrict__ bbase,
                                              const unsigned int* __restrict__ tmp,
                                              ushort* __restrict__ csru,
                                              int* __restrict__ offs,
                                              float* __restrict__ dinv) {
    __shared__ unsigned int ent[MAXB];
    __shared__ int cnt[256];
    __shared__ int boff[256];
    __shared__ int cur[256];
    int b = blockIdx.x, tid = threadIdx.x;
    int base = bbase[b];
    int nb = bbase[b + 1] - base;
    cnt[tid] = 0;
    __syncthreads();
    for (int i = tid; i < nb; i += 256) {
        unsigned int v = tmp[base + i];
        ent[i] = v;
        atomicAdd(&cnt[v & 255], 1);
    }
    __syncthreads();
    int v = cnt[tid];
    boff[tid] = v;
    __syncthreads();
    for (int o = 1; o < 256; o <<= 1) {
        int t = (tid >= o) ? boff[tid - o] : 0;
        __syncthreads();
        boff[tid] += t;
        __syncthreads();
    }
    int excl = boff[tid] - v;
    int node = b * 256 + tid;
    if (node < NN) {
        offs[node] = base + excl;
        dinv[node] = rsqrtf((float)(v + 1));   // +1 self-loop
    }
    cur[tid] = excl;
    __syncthreads();
    for (int i = tid; i < nb; i += 256) {
        unsigned int e = ent[i];
        int bin = e & 255;
        int r = atomicAdd(&cur[bin], 1);
        csru[base + r] = (ushort)(e >> 8);
    }
}

// W[k][n] fp32 -> bf16 hi/lo in B-fragment-contiguous order:
// frag g=(ntile*4+kk)*64+lane holds B[k=kk*32+(lane>>4)*8+j][n=ntile*16+(lane&15)]
__global__ void k_wconv(const float* __restrict__ W, ushort* __restrict__ wh,
                        ushort* __restrict__ wl) {
    int g = blockIdx.x * blockDim.x + threadIdx.x;
    if (g >= 2048) return;
    int ntile = g >> 8;
    int kk = (g >> 6) & 3;
    int lane = g & 63;
    int k0 = kk * 32 + ((lane >> 4) * 8);
    int col = ntile * 16 + (lane & 15);
#pragma unroll
    for (int j = 0; j < 8; ++j) {
        float w = W[(k0 + j) * DD + col];
        unsigned short h = f2bf(w);
        wh[(size_t)g * 8 + j] = h;
        wl[(size_t)g * 8 + j] = f2bf(w - bf2f(h));
    }
}

// MFMA GEMM, split-bf16 (hi*hi + hi*lo + lo*hi ~ fp32 accuracy).
// Reads fp32 X directly, Dekker-splits in-register.
// Epilogue scales rows by dinv and stores bf16 g = dinv * (X@W).
__global__ __launch_bounds__(256) void k_mgemm(const float* __restrict__ X,
                                               const ushort* __restrict__ wh,
                                               const ushort* __restrict__ wl,
                                               const float* __restrict__ dinv,
                                               ushort* __restrict__ G) {
    int wave = threadIdx.x >> 6;
    int lane = threadIdx.x & 63;
    int strip = blockIdx.x * 4 + wave;
    if (strip >= NSTRIP) return;
    int rb = strip << 4;
    int m = lane & 15;
    int quad = lane >> 4;
    const float* ar = X + (size_t)(rb + m) * DD;
    f32x4 acc[8];
#pragma unroll
    for (int t = 0; t < 8; ++t) acc[t] = (f32x4){0.f, 0.f, 0.f, 0.f};
#pragma unroll
    for (int kk = 0; kk < 4; ++kk) {
        float4 xa = *(const float4*)(ar + kk * 32 + quad * 8);
        float4 xb = *(const float4*)(ar + kk * 32 + quad * 8 + 4);
        float xs[8] = {xa.x, xa.y, xa.z, xa.w, xb.x, xb.y, xb.z, xb.w};
        bf8_t ah, al;
#pragma unroll
        for (int j = 0; j < 8; ++j) {
            unsigned short hh = f2bf(xs[j]);
            ah[j] = (short)hh;
            al[j] = (short)f2bf(xs[j] - bf2f(hh));
        }
#pragma unroll
        for (int t = 0; t < 8; ++t) {
            size_t bo = ((size_t)(t * 4 + kk) * 64 + lane) * 8;
            bf8_t bh = *(const bf8_t*)(wh + bo);
            bf8_t bl = *(const bf8_t*)(wl + bo);
            acc[t] = __builtin_amdgcn_mfma_f32_16x16x32_bf16(ah, bh, acc[t], 0, 0, 0);
            acc[t] = __builtin_amdgcn_mfma_f32_16x16x32_bf16(ah, bl, acc[t], 0, 0, 0);
            acc[t] = __builtin_amdgcn_mfma_f32_16x16x32_bf16(al, bh, acc[t], 0, 0, 0);
        }
    }
    // C/D layout (m89-verified): col = lane&15, row = quad*4 + reg
    float dv[4];
#pragma unroll
    for (int r = 0; r < 4; ++r) dv[r] = dinv[rb + quad * 4 + r];
#pragma unroll
    for (int t = 0; t < 8; ++t) {
#pragma unroll
        for (int r = 0; r < 4; ++r)
            G[(size_t)(rb + quad * 4 + r) * DD + t * 16 + m] = f2bf(dv[r] * acc[t][r]);
    }
}

// out[i] = relu( dinv[i] * ( sum_{e: dst==i} g[src_e] + g[i] ) + bias )
// g is bf16 (256B rows), pre-scaled by dinv[src].  One wave per node;
// 32 lanes x ushort4 (8B/lane); halves take interleaved edges, 2x unroll
// -> 4 independent gathers in flight.
__global__ void k_agg(const ushort* __restrict__ g, const float* __restrict__ dinv,
                      const int* __restrict__ offs, const ushort* __restrict__ csru,
                      const float* __restrict__ bias, float* __restrict__ outf) {
    int gid = blockIdx.x * blockDim.x + threadIdx.x;
    int node = gid >> 6;
    if (node >= NN) return;
    int lane = threadIdx.x & 63;
    int half = lane >> 5;
    int c = lane & 31;
    float4 a0 = {0.f, 0.f, 0.f, 0.f};
    float4 a1 = {0.f, 0.f, 0.f, 0.f};
    int e  = offs[node] + half;
    int e1 = offs[node + 1];
    for (; e + 2 < e1; e += 4) {
        int s0 = csru[e];
        int s1 = csru[e + 2];
        ushort4 v0 = *(const ushort4*)(g + (size_t)s0 * DD + 4 * c);
        ushort4 v1 = *(const ushort4*)(g + (size_t)s1 * DD + 4 * c);
        a0.x += bf2f(v0.x); a0.y += bf2f(v0.y); a0.z += bf2f(v0.z); a0.w += bf2f(v0.w);
        a1.x += bf2f(v1.x); a1.y += bf2f(v1.y); a1.z += bf2f(v1.z); a1.w += bf2f(v1.w);
    }
    if (e < e1) {
        int s0 = csru[e];
        ushort4 v0 = *(const ushort4*)(g + (size_t)s0 * DD + 4 * c);
        a0.x += bf2f(v0.x); a0.y += bf2f(v0.y); a0.z += bf2f(v0.z); a0.w += bf2f(v0.w);
    }
    if (half == 0) {  // self-loop term: dinv^2*h = dinv*g, counted once
        ushort4 v = *(const ushort4*)(g + (size_t)node * DD + 4 * c);
        a0.x += bf2f(v.x); a0.y += bf2f(v.y); a0.z += bf2f(v.z); a0.w += bf2f(v.w);
    }
    a0.x += a1.x; a0.y += a1.y; a0.z += a1.z; a0.w += a1.w;
    a0.x += __shfl_xor(a0.x, 32, 64);
    a0.y += __shfl_xor(a0.y, 32, 64);
    a0.z += __shfl_xor(a0.z, 32, 64);
    a0.w += __shfl_xor(a0.w, 32, 64);
    if (half == 0) {
        float di = dinv[node];
        float4 bv = ((const float4*)bias)[c];
        float4 o;
        o.x = fmaxf(di * a0.x + bv.x, 0.f);
        o.y = fmaxf(di * a0.y + bv.y, 0.f);
        o.z = fmaxf(di * a0.z + bv.z, 0.f);
        o.w = fmaxf(di * a0.w + bv.w, 0.f);
        ((float4*)(outf + (size_t)node * DD))[c] = o;
    }
}

extern "C" void kernel_launch(void* const* d_in, const int* in_sizes, int n_in,
                              void* d_out, int out_size, void* d_ws, size_t ws_size,
                              hipStream_t stream) {
    const float* x  = (const float*)d_in[0];
    const int*   ei = (const int*)d_in[1];
    const float* W1 = (const float*)d_in[2];
    const float* b1 = (const float*)d_in[3];
    const float* W2 = (const float*)d_in[4];
    const float* b2 = (const float*)d_in[5];
    float* out = (float*)d_out;

    const int* src = ei;        // edge_index[0]
    const int* dst = ei + NE;   // edge_index[1]

    int*          wsi  = (int*)d_ws;
    float*        wsf  = (float*)d_ws;
    ushort*       wsu  = (ushort*)d_ws;
    unsigned int* wsuw = (unsigned int*)d_ws;
    int*    bcnt  = wsi + OF_BCNT;
    int*    bbase = wsi + OF_BBASE;
    int*    bcur  = wsi + OF_BCUR;
    float*  dinv  = wsf + OF_DINV;
    int*    offs  = wsi + OF_OFFS;
    unsigned int* tmp = wsuw + OF_TMP;
    ushort* csru  = wsu + (size_t)OF_CSRU * 2;
    ushort* gbuf  = wsu + (size_t)OF_G * 2;
    float*  x2    = wsf + OF_X2;
    ushort* w1h   = wsu + (size_t)OF_W1H * 2;
    ushort* w1l   = wsu + (size_t)OF_W1L * 2;
    ushort* w2h   = wsu + (size_t)OF_W2H * 2;
    ushort* w2l   = wsu + (size_t)OF_W2L * 2;

    const int chunks = (NE + CHUNK - 1) / CHUNK;  // 196

    // CSR build: two-level bucket sort (no random global scatter)
    hipLaunchKernelGGL(k_zero,  dim3(1), dim3(256), 0, stream, bcnt);
    hipLaunchKernelGGL(k_hist,  dim3(chunks), dim3(256), 0, stream, dst, bcnt);
    hipLaunchKernelGGL(k_bscan, dim3(1), dim3(256), 0, stream, bcnt, bbase, bcur, offs);
    hipLaunchKernelGGL(k_shuf,  dim3(chunks), dim3(256), 0, stream, src, dst, bcur, tmp);
    hipLaunchKernelGGL(k_sort,  dim3(NB), dim3(256), 0, stream, bbase, tmp, csru, offs, dinv);

    hipLaunchKernelGGL(k_wconv, dim3(8), dim3(256), 0, stream, W1, w1h, w1l);
    hipLaunchKernelGGL(k_wconv, dim3(8), dim3(256), 0, stream, W2, w2h, w2l);

    const int gblocks = (NSTRIP + 3) / 4;  // 782

    // layer 1: g = dinv*(x @ W1) (MFMA, bf16) ; agg -> relu(dinv*sum + b1) fp32
    hipLaunchKernelGGL(k_mgemm, dim3(gblocks), dim3(256), 0, stream, x, w1h, w1l, dinv, gbuf);
    hipLaunchKernelGGL(k_agg,   dim3((NN * 64 + 255) / 256), dim3(256), 0, stream,
                       gbuf, dinv, offs, csru, b1, x2);
    // layer 2
    hipLaunchKernelGGL(k_mgemm, dim3(gblocks), dim3(256), 0, stream, x2, w2h, w2l, dinv, gbuf);
    hipLaunchKernelGGL(k_agg,   dim3((NN * 64 + 255) / 256), dim3(256), 0, stream,
                       gbuf, dinv, offs, csru, b2, out);
}